// Round 12
// baseline (12862.352 us; speedup 1.0000x reference)
//
#include <hip/hip_runtime.h>

#define NB 256
#define NT 512
#define TT 1024
#define HH 512
#define BATCH 256
#define UB 16     // units per block (32 slots cover 512 units)
#define BGB 16    // batches per bg; 16 bgs; block serves a PAIR of bgs

using v8s   = __attribute__((ext_vector_type(8))) short;
using f32x4 = __attribute__((ext_vector_type(4))) float;

// ---- LDS layout (bytes) ----
// O_STG (bounce) is deliberately ALIASED by O_SCR/O_SO (r8-proven trick):
// after the one-time GRAB into registers, loop-time SCR writes clobber STG,
// so the compiler cannot rematerialize the register tiles from LDS.
#define O_STG  0        // 32768: bounce buffer (staging only)
#define O_SCR  0        // 2 x 11520: exchange [kh][tau9][row16 x stride20] f32
#define O_SO   23040    // 128: out-col exchange [kh][row16] f32
#define O_N1   32768    // 32768: permanent Whh1 n-gate tile
#define O_WOUT 65536    // 2048: Wout col hi+lo
#define O_ZERO 67584    // 16
#define LDS_BYTES 67600

#define SLOT_SH 524288  // shorts per ring generation: 16 bgs x 32768 shorts

__device__ __forceinline__ float sigf(float v)   { return 1.f / (1.f + __expf(-v)); }
__device__ __forceinline__ float tanhf_(float v) { return 2.f / (1.f + __expf(-2.f * v)) - 1.f; }

__device__ __forceinline__ unsigned short bf16_rne(float f) {
    union { float f; unsigned u; } a; a.f = f;
    unsigned r = (a.u + 0x7fffu + ((a.u >> 16) & 1u)) >> 16;
    return (unsigned short)r;
}
__device__ __forceinline__ float bf16_f(unsigned short h) {
    union { unsigned u; float f; } a; a.u = ((unsigned)h) << 16; return a.f;
}
__device__ __forceinline__ f32x4 MF(v8s a, v8s b, f32x4 c) {
    return __builtin_amdgcn_mfma_f32_16x16x32_bf16(a, b, c, 0, 0, 0);
}
#define T3(ACC, AH_, AL_, BH_, BL_) \
    ACC = MF(AH_, BH_, ACC); ACC = MF(AL_, BH_, ACC); ACC = MF(AH_, BL_, ACC);

// write-through: h reaches chip coherence point before arrival RMW
#define GST2(addr, val) \
    asm volatile("global_store_short %0, %1, off sc0 sc1" \
                 :: "v"(addr), "v"((unsigned)(val)) : "memory");

// Split-phase per-bg barrier (fan-in 32, placement-free, r8-proven RMW shape)
__device__ __forceinline__ void bar_arrive(unsigned* cnt, int tid) {
    asm volatile("s_waitcnt vmcnt(0)" ::: "memory");
    __syncthreads();
    if (tid == 0)
        __hip_atomic_fetch_add(cnt, 1u, __ATOMIC_RELAXED, __HIP_MEMORY_SCOPE_AGENT);
}
__device__ __forceinline__ void bar_wait(unsigned* cnt, int tid, unsigned target, bool fence) {
    if (tid == 0) {
        while (__hip_atomic_load(cnt, __ATOMIC_RELAXED, __HIP_MEMORY_SCOPE_AGENT) < target)
            __builtin_amdgcn_s_sleep(1);
        if (fence)
            __builtin_amdgcn_fence(__ATOMIC_ACQUIRE, "agent");
    }
    __syncthreads();
}

// x: [B][T] -> xT: [T][B]
__global__ __launch_bounds__(256) void k_transpose(const float* __restrict__ x,
                                                   float* __restrict__ xT) {
    __shared__ float tile[64][65];
    const int bt = blockIdx.x, bb = blockIdx.y;
    const int lt = threadIdx.x & 63, lb = threadIdx.x >> 6;
    #pragma unroll 4
    for (int i = 0; i < 16; ++i) {
        int row = lb + i * 4;
        tile[row][lt] = x[(size_t)(bb * 64 + row) * TT + bt * 64 + lt];
    }
    __syncthreads();
    #pragma unroll 4
    for (int i = 0; i < 16; ++i) {
        int row = lb + i * 4;
        xT[(size_t)(bt * 64 + row) * BATCH + bb * 64 + lt] = tile[lt][row];
    }
}

// stage one 16-unit x 512-k gate tile (bf16 hi+lo) into O_STG (r5-verified layout)
#define STAGE_TILE(SRC) \
    for (int i = tid; i < 16 * 512; i += NT) { \
        int n = i >> 9, k = i & 511; \
        float f = (SRC)[(size_t)(u0 + n) * HH + k]; \
        unsigned short hi = bf16_rne(f), lo = bf16_rne(f - bf16_f(hi)); \
        int s = k >> 5, g = (k >> 3) & 3, j = k & 7, ln = g * 16 + n; \
        int base = O_STG + s * 2048 + ln * 16 + j * 2; \
        *(unsigned short*)(lds_b + base) = hi; \
        *(unsigned short*)(lds_b + base + 1024) = lo; }

#define GRAB(RB) { \
    const char* bp = lds_b + O_STG + lane * 16; \
    _Pragma("unroll") for (int s8 = 0; s8 < 8; ++s8) { \
        RB[s8][0] = *(const v8s*)(bp + (kh * 8 + s8) * 2048); \
        RB[s8][1] = *(const v8s*)(bp + (kh * 8 + s8) * 2048 + 1024); } }

#define PUB(TAU, A0) \
    _Pragma("unroll") for (int j = 0; j < 4; ++j) \
        sk[(TAU) * 320 + (g4 * 4 + j) * 20 + n16] = (A0)[j];

// One cohort phase: pass -> exchange -> epilogue -> arrive
#define PHASE(BGI, H1PV, H2PV, GBV, CNTP)                                          \
{                                                                                  \
    const unsigned short* __restrict__ setR =                                      \
        hws + (size_t)(t & rmask) * SLOT_SH + (size_t)(BGI) * 32768;               \
    unsigned short* __restrict__ setW =                                            \
        hws + (size_t)((t + 1) & rmask) * SLOT_SH + (size_t)(BGI) * 32768;         \
    const unsigned short* __restrict__ p1h = setR + rowA;                          \
    const unsigned short* __restrict__ p1l = setR + 8192 + rowA;                   \
    const unsigned short* __restrict__ p2h = setR + 16384 + rowA;                  \
    const unsigned short* __restrict__ p2l = setR + 24576 + rowA;                  \
    f32x4 ac0 = {0.f,0.f,0.f,0.f}, ac1 = {0.f,0.f,0.f,0.f};                        \
    if (tg == 0) {                                                                 \
        f32x4 ao0 = {0.f,0.f,0.f,0.f};                                             \
        _Pragma("unroll") for (int sl = 0; sl < 8; ++sl) {                         \
            const v8s ah_ = *(const v8s*)(p2h + sl * 32);                          \
            const v8s al_ = *(const v8s*)(p2l + sl * 32);                          \
            T3(ac0, ah_, al_, RB0[sl][0], RB0[sl][1])                              \
            T3(ac1, ah_, al_, RB1[sl][0], RB1[sl][1])                              \
            if (doOut) {                                                           \
                v8s wh = *(const v8s*)(BoP + sl * bos);                            \
                v8s wl = *(const v8s*)(BolP + sl * bos);                           \
                T3(ao0, ah_, al_, wh, wl)                                          \
            }                                                                      \
        }                                                                          \
        PUB(3, ac0) PUB(4, ac1)                                                    \
        if (doOut && n16 == 0) {                                                   \
            float* sp = (float*)(lds_b + O_SO) + kh * 16;                          \
            _Pragma("unroll") for (int j = 0; j < 4; ++j) sp[g4 * 4 + j] = ao0[j]; \
        }                                                                          \
    } else if (tg == 1) {                                                          \
        _Pragma("unroll") for (int sl = 0; sl < 8; ++sl) {                         \
            const v8s ah_ = *(const v8s*)(p1h + sl * 32);                          \
            const v8s al_ = *(const v8s*)(p1l + sl * 32);                          \
            T3(ac0, ah_, al_, RB0[sl][0], RB0[sl][1])                              \
            T3(ac1, ah_, al_, RB1[sl][0], RB1[sl][1])                              \
        }                                                                          \
        PUB(0, ac0) PUB(1, ac1)                                                    \
    } else if (tg == 2) {                                                          \
        _Pragma("unroll") for (int sl = 0; sl < 8; ++sl) {                         \
            const v8s ah_ = *(const v8s*)(p1h + sl * 32);                          \
            const v8s al_ = *(const v8s*)(p1l + sl * 32);                          \
            T3(ac0, ah_, al_, RB0[sl][0], RB0[sl][1])                              \
            const v8s ch_ = *(const v8s*)(p2h + sl * 32);                          \
            const v8s cl_ = *(const v8s*)(p2l + sl * 32);                          \
            T3(ac1, ch_, cl_, RB1[sl][0], RB1[sl][1])                              \
        }                                                                          \
        PUB(2, ac0) PUB(5, ac1)                                                    \
    } else {                                                                       \
        f32x4 an0 = {0.f,0.f,0.f,0.f};                                             \
        _Pragma("unroll") for (int sl = 0; sl < 8; ++sl) {                         \
            const v8s ah_ = *(const v8s*)(p1h + sl * 32);                          \
            const v8s al_ = *(const v8s*)(p1l + sl * 32);                          \
            T3(ac0, ah_, al_, RB0[sl][0], RB0[sl][1])                              \
            T3(ac1, ah_, al_, RB1[sl][0], RB1[sl][1])                              \
            const v8s nh = *(const v8s*)(n1p + (kh * 8 + sl) * 2048);              \
            const v8s nl = *(const v8s*)(n1p + (kh * 8 + sl) * 2048 + 1024);       \
            T3(an0, ah_, al_, nh, nl)                                              \
        }                                                                          \
        PUB(6, ac0) PUB(7, ac1) PUB(8, an0)                                        \
    }                                                                              \
    __syncthreads();                                                               \
    if (tid < 256) {                                                               \
        const float* sA = (const float*)(lds_b + O_SCR);                           \
        const float* sB = sA + 2880;                                               \
        const int ei = b * 20 + u;                                                 \
        float v0 = sA[0 * 320 + ei] + sB[0 * 320 + ei];                            \
        float v1 = sA[1 * 320 + ei] + sB[1 * 320 + ei];                            \
        float v2 = sA[2 * 320 + ei] + sB[2 * 320 + ei];                            \
        float v3 = sA[3 * 320 + ei] + sB[3 * 320 + ei];                            \
        float v4 = sA[4 * 320 + ei] + sB[4 * 320 + ei];                            \
        float v5 = sA[5 * 320 + ei] + sB[5 * 320 + ei];                            \
        float v6 = sA[6 * 320 + ei] + sB[6 * 320 + ei];                            \
        float v7 = sA[7 * 320 + ei] + sB[7 * 320 + ei];                            \
        float v8 = sA[8 * 320 + ei] + sB[8 * 320 + ei];                            \
        float r2 = sigf(v0 + v3 + b2r);                                            \
        float z2 = sigf(v1 + v4 + b2z);                                            \
        float n2 = tanhf_(v2 + b2in + r2 * (v5 + b2hn));                           \
        float h2n = (1.f - z2) * n2 + z2 * (H2PV);                                 \
        if (t < TT) {                                                              \
            H2PV = h2n;                                                            \
            unsigned short hi = bf16_rne(h2n), lo = bf16_rne(h2n - bf16_f(hi));    \
            GST2(setW + 16384 + (size_t)b * 512 + gu, hi);                         \
            GST2(setW + 24576 + (size_t)b * 512 + gu, lo);                         \
        }                                                                          \
        float xv = (t + 1 < TT) ? xT[(size_t)(t + 1) * BATCH + (GBV)] : 0.f;       \
        float r1 = sigf(xv * w1r + v6 + b1r);                                      \
        float z1 = sigf(xv * w1z + v7 + b1z);                                      \
        float n1 = tanhf_(xv * w1n + b1ni + r1 * (v8 + b1nh));                     \
        float h1n = (1.f - z1) * n1 + z1 * (H1PV);                                 \
        if (t + 1 < TT) {                                                          \
            H1PV = h1n;                                                            \
            unsigned short hi = bf16_rne(h1n), lo = bf16_rne(h1n - bf16_f(hi));    \
            GST2(setW + (size_t)b * 512 + gu, hi);                                 \
            GST2(setW + 8192 + (size_t)b * 512 + gu, lo);                          \
        }                                                                          \
        if (doOut && u == 0 && t >= 1) {                                           \
            const float* sp = (const float*)(lds_b + O_SO);                        \
            out[(size_t)(GBV) * TT + (t - 1)] = sp[b] + sp[16 + b] + bo;           \
        }                                                                          \
    }                                                                              \
    bar_arrive(CNTP, tid);                                                         \
}

__global__ __launch_bounds__(NT, 1) void gru_mfma(
    const float* __restrict__ xT,
    const float* __restrict__ Wih1, const float* __restrict__ Whh1,
    const float* __restrict__ bih1, const float* __restrict__ bhh1,
    const float* __restrict__ Wih2, const float* __restrict__ Whh2,
    const float* __restrict__ bih2, const float* __restrict__ bhh2,
    const float* __restrict__ Wout, const float* __restrict__ bout,
    float* __restrict__ out,
    unsigned short* __restrict__ hws,
    unsigned* __restrict__ barr,
    int rmask, int invmask)
{
    extern __shared__ char lds_b[];
    const int tid = threadIdx.x, blk = blockIdx.x;

    // static decomposition: 8 pairs x 32 slots; pair p serves bgs {2p, 2p+1}
    const int pair = blk >> 5;
    const int slot = blk & 31;
    const int u0 = slot * UB;
    const bool doOut = (slot == 0);
    const int bgA = 2 * pair, bgB = 2 * pair + 1;
    unsigned* cntA = barr + bgA * 64;
    unsigned* cntB = barr + bgB * 64;

    const int w = tid >> 6, lane = tid & 63;
    const int n16 = lane & 15, g4 = lane >> 4;
    const int kh = w & 1, tg = w >> 1;

    // ---- weight staging: 8 reg-tiles via LDS bounce + n1 tile + Wout ----
    if (tid < 4) ((unsigned*)(lds_b + O_ZERO))[tid] = 0;
    v8s RB0[8][2], RB1[8][2];
    const size_t G = (size_t)HH * HH;
    STAGE_TILE(Whh2)          __syncthreads(); if (tg == 0) GRAB(RB0) __syncthreads();
    STAGE_TILE(Whh2 + G)      __syncthreads(); if (tg == 0) GRAB(RB1) __syncthreads();
    STAGE_TILE(Wih2)          __syncthreads(); if (tg == 1) GRAB(RB0) __syncthreads();
    STAGE_TILE(Wih2 + G)      __syncthreads(); if (tg == 1) GRAB(RB1) __syncthreads();
    STAGE_TILE(Wih2 + 2 * G)  __syncthreads(); if (tg == 2) GRAB(RB0) __syncthreads();
    STAGE_TILE(Whh2 + 2 * G)  __syncthreads(); if (tg == 2) GRAB(RB1) __syncthreads();
    STAGE_TILE(Whh1)          __syncthreads(); if (tg == 3) GRAB(RB0) __syncthreads();
    STAGE_TILE(Whh1 + G)      __syncthreads(); if (tg == 3) GRAB(RB1) __syncthreads();
    for (int i = tid; i < 16 * 512; i += NT) {        // Whh1 n-gate -> O_N1
        int n = i >> 9, k = i & 511;
        float f = Whh1[2 * G + (size_t)(u0 + n) * HH + k];
        unsigned short hi = bf16_rne(f), lo = bf16_rne(f - bf16_f(hi));
        int s = k >> 5, g = (k >> 3) & 3, j = k & 7, ln = g * 16 + n;
        int base = O_N1 + s * 2048 + ln * 16 + j * 2;
        *(unsigned short*)(lds_b + base) = hi;
        *(unsigned short*)(lds_b + base + 1024) = lo;
    }
    for (int k = tid; k < 512; k += NT) {             // Wout col
        float f = Wout[k];
        unsigned short hi = bf16_rne(f), lo = bf16_rne(f - bf16_f(hi));
        int s = k >> 5, g = (k >> 3) & 3, j = k & 7;
        int base = O_WOUT + s * 64 + g * 16 + j * 2;
        *(unsigned short*)(lds_b + base) = hi;
        *(unsigned short*)(lds_b + base + 1024) = lo;
    }

    // ---- per-thread epilogue constants: thread = (unit u, local batch b) ----
    const int u = tid & 15, b = (tid >> 4) & 15;      // b in [0,16)
    const int gu = u0 + u;
    const int gbA = bgA * BGB + b, gbB = bgB * BGB + b;
    const float b2r  = bih2[gu] + bhh2[gu];
    const float b2z  = bih2[HH + gu] + bhh2[HH + gu];
    const float b2in = bih2[2 * HH + gu], b2hn = bhh2[2 * HH + gu];
    const float w1r = Wih1[gu], w1z = Wih1[HH + gu], w1n = Wih1[2 * HH + gu];
    const float b1r = bih1[gu] + bhh1[gu];
    const float b1z = bih1[HH + gu] + bhh1[HH + gu];
    const float b1ni = bih1[2 * HH + gu], b1nh = bhh1[2 * HH + gu];
    const float bo = bout[0];

    // ---- prologue: {h1(0), h2(-1)=0} for BOTH cohorts into generation 0 ----
    float h1A = 0.f, h2A = 0.f, h1B = 0.f, h2B = 0.f;
    if (tid < 256) {
        unsigned short* sA0 = hws + (size_t)bgA * 32768;
        unsigned short* sB0 = hws + (size_t)bgB * 32768;
        {
            float x0 = xT[gbA];
            float r = sigf(x0 * w1r + b1r);
            float z = sigf(x0 * w1z + b1z);
            float n = tanhf_(x0 * w1n + b1ni + r * b1nh);
            h1A = (1.f - z) * n;
            unsigned short hi = bf16_rne(h1A), lo = bf16_rne(h1A - bf16_f(hi));
            GST2(sA0 + (size_t)b * 512 + gu, hi);
            GST2(sA0 + 8192 + (size_t)b * 512 + gu, lo);
            GST2(sA0 + 16384 + (size_t)b * 512 + gu, 0u);
            GST2(sA0 + 24576 + (size_t)b * 512 + gu, 0u);
        }
        {
            float x0 = xT[gbB];
            float r = sigf(x0 * w1r + b1r);
            float z = sigf(x0 * w1z + b1z);
            float n = tanhf_(x0 * w1n + b1ni + r * b1nh);
            h1B = (1.f - z) * n;
            unsigned short hi = bf16_rne(h1B), lo = bf16_rne(h1B - bf16_f(hi));
            GST2(sB0 + (size_t)b * 512 + gu, hi);
            GST2(sB0 + 8192 + (size_t)b * 512 + gu, lo);
            GST2(sB0 + 16384 + (size_t)b * 512 + gu, 0u);
            GST2(sB0 + 24576 + (size_t)b * 512 + gu, 0u);
        }
    }

    // B pointers for LDS-resident tiles
    const char* n1p  = lds_b + O_N1 + lane * 16;
    const char* BoP  = (n16 == 0) ? lds_b + O_WOUT + kh * 512 + g4 * 16
                                  : lds_b + O_ZERO;
    const char* BolP = (n16 == 0) ? BoP + 1024 : lds_b + O_ZERO;
    const int bos = (n16 == 0) ? 64 : 0;
    float* sk = (float*)(lds_b + O_SCR) + kh * 2880;

    const int rowA = n16 * 512 + kh * 256 + g4 * 8;   // per-lane A offset

    bar_arrive(cntA, tid);   // counts toward epoch 1 (h(0) ready)
    bar_arrive(cntB, tid);

    // ================= main recurrence: two-cohort pipeline =================
    for (int t = 0; t <= TT; ++t) {
        const bool fc = ((t & invmask) == invmask) || (t == 0);
        bar_wait(cntA, tid, (unsigned)(t + 1) * 32u, fc);
        PHASE(bgA, h1A, h2A, gbA, cntA)
        bar_wait(cntB, tid, (unsigned)(t + 1) * 32u, fc);
        PHASE(bgB, h1B, h2B, gbB, cntB)
    }
}

extern "C" void kernel_launch(void* const* d_in, const int* in_sizes, int n_in,
                              void* d_out, int out_size, void* d_ws, size_t ws_size,
                              hipStream_t stream) {
    const float* x    = (const float*)d_in[0];
    const float* Wih1 = (const float*)d_in[1];
    const float* Whh1 = (const float*)d_in[2];
    const float* bih1 = (const float*)d_in[3];
    const float* bhh1 = (const float*)d_in[4];
    const float* Wih2 = (const float*)d_in[5];
    const float* Whh2 = (const float*)d_in[6];
    const float* bih2 = (const float*)d_in[7];
    const float* bhh2 = (const float*)d_in[8];
    const float* Wout = (const float*)d_in[9];
    const float* bout = (const float*)d_in[10];
    float* outp = (float*)d_out;

    // ws layout: [ring: R MB][xT: 1 MB][barr: 8 KB]
    const size_t MB = 1048576;
    size_t avail = (ws_size > MB + 8192) ? ws_size - MB - 8192 : 2 * MB;
    int R = 2;
    while (R < 64 && (size_t)(R * 2) * MB <= avail) R *= 2;
    const int INVP = (R >= 4) ? (R / 2) : 1;

    unsigned short* hws = (unsigned short*)d_ws;
    float* xTp     = (float*)((char*)d_ws + (size_t)R * MB);
    unsigned* barr = (unsigned*)((char*)d_ws + (size_t)R * MB + MB);

    hipMemsetAsync((void*)barr, 0, 8192, stream);
    k_transpose<<<dim3(16, 4), 256, 0, stream>>>(x, xTp);

    hipFuncSetAttribute((const void*)gru_mfma,
                        hipFuncAttributeMaxDynamicSharedMemorySize, LDS_BYTES);

    int rmask = R - 1, invmask = INVP - 1;
    void* args[] = { (void*)&xTp,
                     (void*)&Wih1, (void*)&Whh1, (void*)&bih1, (void*)&bhh1,
                     (void*)&Wih2, (void*)&Whh2, (void*)&bih2, (void*)&bhh2,
                     (void*)&Wout, (void*)&bout,
                     (void*)&outp, (void*)&hws, (void*)&barr,
                     (void*)&rmask, (void*)&invmask };
    hipLaunchCooperativeKernel((void*)gru_mfma, dim3(NB), dim3(NT),
                               args, LDS_BYTES, stream);
}